// Round 1
// baseline (69.252 us; speedup 1.0000x reference)
//
#include <hip/hip_runtime.h>
#include <math.h>

#define MARGIN 0.2f
#define NEG_WEIGHT 0.5f

constexpr int Bc = 64, Nc = 16, Lc = 1024, DH = 64, Ac = 8;
constexpr int NSAMP = Bc * Ac;   // 512

__device__ __forceinline__ float pdist(float x2, float y2, float diff2) {
    // poincare_dist with C=1, faithful to reference clamps
    x2 = fminf(x2, 0.999999f);
    y2 = fminf(y2, 0.999999f);
    float num = 2.0f * diff2;
    float den = (1.0f - x2) * (1.0f - y2);
    float ratio = num / fmaxf(den, 1e-15f);
    float z = 1.0f + fmaxf(ratio, 1.0f + 1e-7f);
    return acoshf(z);
}

__global__ __launch_bounds__(256) void sample_kernel(
    const float* __restrict__ h_curr,
    const float* __restrict__ demo_h,
    const int*   __restrict__ align_idx,
    const int*   __restrict__ lookahead_p,
    float* __restrict__ ws)
{
    const int s    = blockIdx.x;       // 0..511 sample id
    const int b    = s / Ac;
    const int tid  = threadIdx.x;
    const int wave = tid >> 6;         // 0..3
    const int lane = tid & 63;
    const int grp  = lane >> 4;        // 0..3 : which row within the wave's batch
    const int gl   = lane & 15;        // 0..15: which float4 of the row

    const int n0 = align_idx[s * 2 + 0];
    const int l0 = align_idx[s * 2 + 1];
    const int lk = lookahead_p[0];
    const int lt = l0 + lk;
    const bool valid = (lt >= 0) && (lt < Lc);

    if (!valid) {
        if (tid == 0) {
            ws[s * 4 + 0] = 0.0f; ws[s * 4 + 1] = 0.0f;
            ws[s * 4 + 2] = 0.0f; ws[s * 4 + 3] = 0.0f;
        }
        return;
    }
    const int lt_c = min(max(lt, 0), Lc - 1);

    const float* __restrict__ xrow = h_curr + (size_t)b * DH;
    const float* __restrict__ seq  = demo_h + (((size_t)b * Nc + (size_t)n0) * Lc) * DH;

    // x fragment: 4 consecutive dims (same across the 4 groups of a wave)
    const float4 xv = *reinterpret_cast<const float4*>(xrow + gl * 4);
    float x2 = xv.x * xv.x + xv.y * xv.y + xv.z * xv.z + xv.w * xv.w;
    #pragma unroll
    for (int m = 1; m < 16; m <<= 1) x2 += __shfl_xor(x2, m, 64);

    // d_pos: row lt_c (computed redundantly in every 16-lane group)
    float d_pos;
    {
        const float4 tv = *reinterpret_cast<const float4*>(seq + (size_t)lt_c * DH + gl * 4);
        float dx = xv.x - tv.x, dy = xv.y - tv.y, dz = xv.z - tv.z, dw = xv.w - tv.w;
        float d2 = dx * dx + dy * dy + dz * dz + dw * dw;
        float y2 = tv.x * tv.x + tv.y * tv.y + tv.z * tv.z + tv.w * tv.w;
        #pragma unroll
        for (int m = 1; m < 16; m <<= 1) {
            d2 += __shfl_xor(d2, m, 64);
            y2 += __shfl_xor(y2, m, 64);
        }
        d_pos = pdist(x2, y2, d2);
    }

    // negatives: rows base = wave*4 + grp, stepping 16 -> covers 0..1023
    float hinge_acc = 0.0f, cnt_acc = 0.0f;
    for (int row = wave * 4 + grp; row < Lc; row += 16) {
        const float4 yv = *reinterpret_cast<const float4*>(seq + (size_t)row * DH + gl * 4);
        float dx = xv.x - yv.x, dy = xv.y - yv.y, dz = xv.z - yv.z, dw = xv.w - yv.w;
        float d2 = dx * dx + dy * dy + dz * dz + dw * dw;
        float y2 = yv.x * yv.x + yv.y * yv.y + yv.z * yv.z + yv.w * yv.w;
        #pragma unroll
        for (int m = 1; m < 16; m <<= 1) {
            d2 += __shfl_xor(d2, m, 64);
            y2 += __shfl_xor(y2, m, 64);
        }
        float dneg = pdist(x2, y2, d2);
        if (row > lt) {
            hinge_acc += fmaxf(MARGIN - dneg + d_pos, 0.0f);
            cnt_acc   += 1.0f;
        }
    }

    // each value is duplicated x16 within its group -> wave reduce then /16
    #pragma unroll
    for (int m = 1; m < 64; m <<= 1) {
        hinge_acc += __shfl_xor(hinge_acc, m, 64);
        cnt_acc   += __shfl_xor(cnt_acc,   m, 64);
    }
    hinge_acc *= (1.0f / 16.0f);
    cnt_acc   *= (1.0f / 16.0f);

    __shared__ float sh_h[4], sh_c[4];
    if (lane == 0) { sh_h[wave] = hinge_acc; sh_c[wave] = cnt_acc; }
    __syncthreads();
    if (tid == 0) {
        float ht = sh_h[0] + sh_h[1] + sh_h[2] + sh_h[3];
        float ct = sh_c[0] + sh_c[1] + sh_c[2] + sh_c[3];
        float per_sample = ht / fmaxf(ct, 1.0f);
        float has_neg = (ct > 0.0f) ? 1.0f : 0.0f;
        ws[s * 4 + 0] = d_pos;            // valid==1 here -> d_pos * vf
        ws[s * 4 + 1] = 1.0f;             // vf
        ws[s * 4 + 2] = per_sample * has_neg;
        ws[s * 4 + 3] = has_neg;
    }
}

__global__ __launch_bounds__(256) void reduce_kernel(
    const float* __restrict__ ws, float* __restrict__ out)
{
    __shared__ float4 sh[256];
    const int tid = threadIdx.x;
    float4 acc = make_float4(0.0f, 0.0f, 0.0f, 0.0f);
    for (int s = tid; s < NSAMP; s += 256) {
        acc.x += ws[s * 4 + 0];
        acc.y += ws[s * 4 + 1];
        acc.z += ws[s * 4 + 2];
        acc.w += ws[s * 4 + 3];
    }
    sh[tid] = acc;
    __syncthreads();
    for (int off = 128; off > 0; off >>= 1) {
        if (tid < off) {
            sh[tid].x += sh[tid + off].x;
            sh[tid].y += sh[tid + off].y;
            sh[tid].z += sh[tid + off].z;
            sh[tid].w += sh[tid + off].w;
        }
        __syncthreads();
    }
    if (tid == 0) {
        float pos_term = sh[0].x / fmaxf(sh[0].y, 1.0f);
        float neg_term = sh[0].z / fmaxf(sh[0].w, 1.0f);
        out[0] = pos_term + NEG_WEIGHT * neg_term;
    }
}

extern "C" void kernel_launch(void* const* d_in, const int* in_sizes, int n_in,
                              void* d_out, int out_size, void* d_ws, size_t ws_size,
                              hipStream_t stream) {
    const float* h_curr    = (const float*)d_in[0];
    const float* demo_h    = (const float*)d_in[1];
    const int*   align_idx = (const int*)d_in[2];
    const int*   lookahead = (const int*)d_in[3];
    float* out = (float*)d_out;
    float* ws  = (float*)d_ws;

    sample_kernel<<<NSAMP, 256, 0, stream>>>(h_curr, demo_h, align_idx, lookahead, ws);
    reduce_kernel<<<1, 256, 0, stream>>>(ws, out);
}

// Round 2
// 26.619 us; speedup vs baseline: 2.6016x; 2.6016x over previous
//
#include <hip/hip_runtime.h>
#include <math.h>

#define MARGIN 0.2f
#define NEG_WEIGHT 0.5f

constexpr int Bc = 64, Nc = 16, Lc = 1024, DH = 64, Ac = 8;
constexpr int NSAMP = Bc * Ac;            // 512
constexpr int CHUNKS = 16;                // chunks per sample
constexpr int ROWS_PER_CHUNK = Lc / CHUNKS;  // 64 rows, one wave each

__device__ __forceinline__ float fast_acosh(float z) {
    // z >= 1 + 1e-7 guaranteed by clamp
    return __logf(z + __builtin_sqrtf(z * z - 1.0f));
}

__device__ __forceinline__ float pdist(float x2, float y2, float d2) {
    x2 = fminf(x2, 0.999999f);
    y2 = fminf(y2, 0.999999f);
    float num = 2.0f * d2;
    float den = (1.0f - x2) * (1.0f - y2);
    float ratio = num * __builtin_amdgcn_rcpf(fmaxf(den, 1e-15f));
    float z = 1.0f + fmaxf(ratio, 1.0f + 1e-7f);
    return fast_acosh(z);
}

// one wave (64 threads) per block; block = (sample, chunk-of-64-rows)
// lane layout: quad = lane&3 owns dims [quad*16, quad*16+16); rg = lane>>2 owns a row
__global__ __launch_bounds__(64) void sample_kernel(
    const float* __restrict__ h_curr,
    const float* __restrict__ demo_h,
    const int*   __restrict__ align_idx,
    const int*   __restrict__ lookahead_p,
    float* __restrict__ ws)
{
    const int blk  = blockIdx.x;
    const int s    = blk >> 4;         // sample 0..511
    const int c    = blk & 15;         // chunk  0..15
    const int b    = s >> 3;           // s / Ac
    const int lane = threadIdx.x;
    const int quad = lane & 3;
    const int rg   = lane >> 2;        // 0..15

    const int n0 = align_idx[s * 2 + 0];
    const int l0 = align_idx[s * 2 + 1];
    const int lt = l0 + lookahead_p[0];
    const bool valid = (lt >= 0) && (lt < Lc);

    float* wneg = ws + (size_t)(s * CHUNKS + c) * 2;
    float* wpos = ws + (size_t)NSAMP * CHUNKS * 2 + (size_t)s * 2;

    if (!valid) {
        if (lane == 0) {
            wneg[0] = 0.0f; wneg[1] = 0.0f;
            if (c == 0) { wpos[0] = 0.0f; wpos[1] = 0.0f; }
        }
        return;
    }
    const int lt_c = min(max(lt, 0), Lc - 1);

    const float* __restrict__ xrow = h_curr + (size_t)b * DH + quad * 16;
    const float* __restrict__ seq  = demo_h + (((size_t)b * Nc + (size_t)n0) * Lc) * DH;

    // x fragment: 16 dims per lane
    float4 xv[4];
    #pragma unroll
    for (int j = 0; j < 4; ++j)
        xv[j] = *reinterpret_cast<const float4*>(xrow + j * 4);

    float x2 = 0.0f;
    #pragma unroll
    for (int j = 0; j < 4; ++j) {
        x2 = fmaf(xv[j].x, xv[j].x, x2);
        x2 = fmaf(xv[j].y, xv[j].y, x2);
        x2 = fmaf(xv[j].z, xv[j].z, x2);
        x2 = fmaf(xv[j].w, xv[j].w, x2);
    }
    x2 += __shfl_xor(x2, 1, 64);
    x2 += __shfl_xor(x2, 2, 64);   // x2 valid in all lanes of each quad-group

    // d_pos from row lt_c (every row-group reads the same row -> identical result)
    float d_pos;
    {
        const float* rowp = seq + (size_t)lt_c * DH + quad * 16;
        float d2 = 0.0f, y2 = 0.0f;
        #pragma unroll
        for (int j = 0; j < 4; ++j) {
            float4 yv = *reinterpret_cast<const float4*>(rowp + j * 4);
            float dx = xv[j].x - yv.x, dy = xv[j].y - yv.y;
            float dz = xv[j].z - yv.z, dw = xv[j].w - yv.w;
            d2 = fmaf(dx, dx, d2); d2 = fmaf(dy, dy, d2);
            d2 = fmaf(dz, dz, d2); d2 = fmaf(dw, dw, d2);
            y2 = fmaf(yv.x, yv.x, y2); y2 = fmaf(yv.y, yv.y, y2);
            y2 = fmaf(yv.z, yv.z, y2); y2 = fmaf(yv.w, yv.w, y2);
        }
        d2 += __shfl_xor(d2, 1, 64); d2 += __shfl_xor(d2, 2, 64);
        y2 += __shfl_xor(y2, 1, 64); y2 += __shfl_xor(y2, 2, 64);
        d_pos = pdist(x2, y2, d2);
    }

    // negatives: 64 rows of this chunk, 16 rows per pass (one per row-group)
    float hinge_acc = 0.0f, cnt_acc = 0.0f;
    #pragma unroll
    for (int it = 0; it < 4; ++it) {
        const int row = c * ROWS_PER_CHUNK + it * 16 + rg;
        const float* rowp = seq + (size_t)row * DH + quad * 16;
        float d2 = 0.0f, y2 = 0.0f;
        #pragma unroll
        for (int j = 0; j < 4; ++j) {
            float4 yv = *reinterpret_cast<const float4*>(rowp + j * 4);
            float dx = xv[j].x - yv.x, dy = xv[j].y - yv.y;
            float dz = xv[j].z - yv.z, dw = xv[j].w - yv.w;
            d2 = fmaf(dx, dx, d2); d2 = fmaf(dy, dy, d2);
            d2 = fmaf(dz, dz, d2); d2 = fmaf(dw, dw, d2);
            y2 = fmaf(yv.x, yv.x, y2); y2 = fmaf(yv.y, yv.y, y2);
            y2 = fmaf(yv.z, yv.z, y2); y2 = fmaf(yv.w, yv.w, y2);
        }
        d2 += __shfl_xor(d2, 1, 64); d2 += __shfl_xor(d2, 2, 64);
        y2 += __shfl_xor(y2, 1, 64); y2 += __shfl_xor(y2, 2, 64);
        float dneg = pdist(x2, y2, d2);
        if (row > lt) {
            hinge_acc += fmaxf(MARGIN - dneg + d_pos, 0.0f);
            cnt_acc   += 1.0f;
        }
    }

    // values are uniform within each quad; sum across the 16 row-groups only
    #pragma unroll
    for (int m = 4; m < 64; m <<= 1) {
        hinge_acc += __shfl_xor(hinge_acc, m, 64);
        cnt_acc   += __shfl_xor(cnt_acc,   m, 64);
    }

    if (lane == 0) {
        wneg[0] = hinge_acc;
        wneg[1] = cnt_acc;
        if (c == 0) { wpos[0] = d_pos; wpos[1] = 1.0f; }
    }
}

__global__ __launch_bounds__(256) void reduce_kernel(
    const float* __restrict__ ws, float* __restrict__ out)
{
    const int tid = threadIdx.x;
    float pn = 0.0f, pv = 0.0f, nn = 0.0f, nc = 0.0f;
    for (int s = tid; s < NSAMP; s += 256) {
        float h = 0.0f, ct = 0.0f;
        #pragma unroll
        for (int c = 0; c < CHUNKS; ++c) {
            h  += ws[(size_t)(s * CHUNKS + c) * 2 + 0];
            ct += ws[(size_t)(s * CHUNKS + c) * 2 + 1];
        }
        float per_sample = h / fmaxf(ct, 1.0f);
        float has_neg = (ct > 0.0f) ? 1.0f : 0.0f;
        nn += per_sample * has_neg;
        nc += has_neg;
        pn += ws[(size_t)NSAMP * CHUNKS * 2 + (size_t)s * 2 + 0];
        pv += ws[(size_t)NSAMP * CHUNKS * 2 + (size_t)s * 2 + 1];
    }
    __shared__ float4 sh[256];
    sh[tid] = make_float4(pn, pv, nn, nc);
    __syncthreads();
    for (int off = 128; off > 0; off >>= 1) {
        if (tid < off) {
            sh[tid].x += sh[tid + off].x;
            sh[tid].y += sh[tid + off].y;
            sh[tid].z += sh[tid + off].z;
            sh[tid].w += sh[tid + off].w;
        }
        __syncthreads();
    }
    if (tid == 0) {
        float pos_term = sh[0].x / fmaxf(sh[0].y, 1.0f);
        float neg_term = sh[0].z / fmaxf(sh[0].w, 1.0f);
        out[0] = pos_term + NEG_WEIGHT * neg_term;
    }
}

extern "C" void kernel_launch(void* const* d_in, const int* in_sizes, int n_in,
                              void* d_out, int out_size, void* d_ws, size_t ws_size,
                              hipStream_t stream) {
    const float* h_curr    = (const float*)d_in[0];
    const float* demo_h    = (const float*)d_in[1];
    const int*   align_idx = (const int*)d_in[2];
    const int*   lookahead = (const int*)d_in[3];
    float* out = (float*)d_out;
    float* ws  = (float*)d_ws;

    sample_kernel<<<NSAMP * CHUNKS, 64, 0, stream>>>(h_curr, demo_h, align_idx, lookahead, ws);
    reduce_kernel<<<1, 256, 0, stream>>>(ws, out);
}